// Round 10
// baseline (179.806 us; speedup 1.0000x reference)
//
#include <hip/hip_runtime.h>

#define NCAP 5
#define DCAP 5
#define NO 25          // NCAP*DCAP
#define II 256
#define FF 80
#define NROUT 4
#define EPS 1e-7f
#define TSTR 260       // uT row stride in halves (520 B -> ~2-way banks on b128)
#define CSTR 260       // cT row stride in halves

typedef _Float16 f16x8 __attribute__((ext_vector_type(8)));
typedef __fp16 fp16x2 __attribute__((ext_vector_type(2)));
typedef float f32x4 __attribute__((ext_vector_type(4)));

// pack 8 consecutive f32 (two float4) into one f16x8 fragment (4 VALU ops)
__device__ __forceinline__ f16x8 pack8(const float4 a, const float4 c) {
    union { fp16x2 p[4]; f16x8 v; } u;
    u.p[0] = __builtin_amdgcn_cvt_pkrtz(a.x, a.y);
    u.p[1] = __builtin_amdgcn_cvt_pkrtz(a.z, a.w);
    u.p[2] = __builtin_amdgcn_cvt_pkrtz(c.x, c.y);
    u.p[3] = __builtin_amdgcn_cvt_pkrtz(c.z, c.w);
    return u.v;
}

__global__ __launch_bounds__(256, 5)
void capsule_mfma(const float* __restrict__ x, const float* __restrict__ W,
                  float* __restrict__ out) {
    const int b    = blockIdx.x;
    const int t    = threadIdx.x;
    const int lane = t & 63;
    const int wv   = t >> 6;
    const int lr   = lane & 15;   // row/col within 16-tile
    const int lg   = lane >> 4;   // k-group / reg-group

    __shared__ __align__(16) _Float16 uT[32 * TSTR];   // 16640 B : u^T[o][i], rows 25..31 zero
    __shared__ __align__(16) _Float16 cT[16 * CSTR];   // 8320 B  : c[n][i], rows 5..15 junk (unused outputs)
    __shared__ __align__(16) float s_lds[NCAP][8];     // 160 B   : s[n][d]

    // ---- A-fragments (W) straight from global (8 KB, L2-hot). ----
    f16x8 Af[2][3];
#pragma unroll
    for (int ot = 0; ot < 2; ++ot)
#pragma unroll
        for (int ks = 0; ks < 3; ++ks) {
            const int row = ot * 16 + lr;
            const int k0  = ks * 32 + lg * 8;
            if (row < NO && k0 < FF) {
                const float4 a = *reinterpret_cast<const float4*>(&W[row * FF + k0]);
                const float4 c = *reinterpret_cast<const float4*>(&W[row * FF + k0 + 4]);
                Af[ot][ks] = pack8(a, c);
            } else {
                const f16x8 z = {};
                Af[ot][ks] = z;
            }
        }

    // ---- GEMM: wave wv owns x-rows [wv*64, wv*64+64) ----
    const float* __restrict__ xbase = x + (size_t)b * II * FF;

#pragma unroll
    for (int nt = 0; nt < 4; ++nt) {
        const int xrow = wv * 64 + nt * 16 + lr;
        const float* __restrict__ xp = xbase + (size_t)xrow * FF;

        f16x8 Bf[3];
#pragma unroll
        for (int ks = 0; ks < 3; ++ks) {
            const int k0 = ks * 32 + lg * 8;
            if (k0 < FF) {
                const float4 a = *reinterpret_cast<const float4*>(xp + k0);
                const float4 c = *reinterpret_cast<const float4*>(xp + k0 + 4);
                Bf[ks] = pack8(a, c);
            } else {
                const f16x8 z = {};
                Bf[ks] = z;
            }
        }

        f32x4 acc0 = {0.f, 0.f, 0.f, 0.f};
        f32x4 acc1 = {0.f, 0.f, 0.f, 0.f};
#pragma unroll
        for (int ks = 0; ks < 3; ++ks) {
            acc0 = __builtin_amdgcn_mfma_f32_16x16x32_f16(Af[0][ks], Bf[ks], acc0, 0, 0, 0);
            acc1 = __builtin_amdgcn_mfma_f32_16x16x32_f16(Af[1][ks], Bf[ks], acc1, 0, 0, 0);
        }

        // C: lane holds col=i=xrow, rows o = (ot*16) + lg*4 + reg.
        // Write transposed f16: uT[o][i]. Rows 25..31 come from zero-padded W -> 0.
#pragma unroll
        for (int rg = 0; rg < 4; ++rg) {
            uT[(lg * 4 + rg) * TSTR + xrow]        = (_Float16)acc0[rg];
            uT[(16 + lg * 4 + rg) * TSTR + xrow]   = (_Float16)acc1[rg];
        }
    }

    // ---- per-thread u readback (row i = t; written by this thread's own wave) ----
    float u[NO];
#pragma unroll
    for (int o = 0; o < NO; ++o) u[o] = (float)uT[o * TSTR + t];

    // ---- dynamic routing: reduction via MFMA  s = cT[5x256] * uT^T[256x25] ----
    float bb[NCAP];
#pragma unroll
    for (int n = 0; n < NCAP; ++n) bb[n] = 0.f;

#pragma unroll
    for (int r = 0; r < NROUT; ++r) {
        float c[NCAP];
        if (r == 0) {
#pragma unroll
            for (int n = 0; n < NCAP; ++n) c[n] = 0.2f;
        } else {
            float m = bb[0];
#pragma unroll
            for (int n = 1; n < NCAP; ++n) m = fmaxf(m, bb[n]);
            float ssum = 0.f;
#pragma unroll
            for (int n = 0; n < NCAP; ++n) { c[n] = __expf(bb[n] - m); ssum += c[n]; }
            const float inv = __frcp_rn(ssum);
#pragma unroll
            for (int n = 0; n < NCAP; ++n) c[n] *= inv;
        }

        // stage c (f16): cT[n][i]
#pragma unroll
        for (int n = 0; n < NCAP; ++n) cT[n * CSTR + t] = (_Float16)c[n];
        __syncthreads();   // cT ready (and uT ready at r=0, cross-wave)

        // s[n][o] = sum_i c[n][i] * u[i][o] : A=c rows n, B=uT rows o, K=256
        f32x4 s0 = {0.f, 0.f, 0.f, 0.f};
        f32x4 s1 = {0.f, 0.f, 0.f, 0.f};
#pragma unroll
        for (int ks = 0; ks < 8; ++ks) {
            const f16x8 ca = *reinterpret_cast<const f16x8*>(&cT[lr * CSTR + ks * 32 + lg * 8]);
            const f16x8 u0 = *reinterpret_cast<const f16x8*>(&uT[lr * TSTR + ks * 32 + lg * 8]);
            const f16x8 u1 = *reinterpret_cast<const f16x8*>(&uT[(16 + lr) * TSTR + ks * 32 + lg * 8]);
            s0 = __builtin_amdgcn_mfma_f32_16x16x32_f16(ca, u0, s0, 0, 0, 0);
            s1 = __builtin_amdgcn_mfma_f32_16x16x32_f16(ca, u1, s1, 0, 0, 0);
        }

        // extract valid (n, o=5n+d): C layout col=lr(=o-in-tile), row=lg*4+reg(=n)
        if (wv == 0) {
            if (lg == 0) {
                const int n0 = lr / 5;            // 15/5=3 handles lr==15 (o=15,d=0)
                const int d0 = lr - 5 * n0;
                const float v = (lr < 5) ? s0[0] : (lr < 10) ? s0[1]
                              : (lr < 15) ? s0[2] : s0[3];
                s_lds[n0][d0] = v;
                if (lr < 4) s_lds[3][1 + lr] = s1[3];   // n=3, o=16..19 -> d=1..4
            }
            if (lg == 1 && lr >= 4 && lr < 9) s_lds[4][lr - 4] = s1[0];  // n=4, o=20..24
        }
        __syncthreads();   // s ready

        // broadcast-read s[5][5]
        float sarr[NO];
#pragma unroll
        for (int n = 0; n < NCAP; ++n) {
            const float4 v4 = *reinterpret_cast<const float4*>(&s_lds[n][0]);
            sarr[n * 5 + 0] = v4.x; sarr[n * 5 + 1] = v4.y;
            sarr[n * 5 + 2] = v4.z; sarr[n * 5 + 3] = v4.w;
            sarr[n * 5 + 4] = s_lds[n][4];
        }

        if (r < NROUT - 1) {
#pragma unroll
            for (int n = 0; n < NCAP; ++n) {
                float sn = 0.f, dot = 0.f;
#pragma unroll
                for (int d = 0; d < DCAP; ++d) {
                    const float sv = sarr[n * DCAP + d];
                    sn  = fmaf(sv, sv, sn);
                    dot = fmaf(sv, u[n * DCAP + d], dot);
                }
                const float scale = sn * __frsqrt_rn(sn + EPS) * __frcp_rn(1.f + sn);
                bb[n] += dot * scale;
            }
        } else {
            if (t < NO) {
                const int n0 = t / DCAP;
                float sn = 0.f;
#pragma unroll
                for (int d = 0; d < DCAP; ++d) {
                    const float sv = sarr[n0 * DCAP + d];
                    sn = fmaf(sv, sv, sn);
                }
                const float scale = sn * __frsqrt_rn(sn + EPS) * __frcp_rn(1.f + sn);
                out[(size_t)b * NO + t] = sarr[t] * scale;
            }
        }
    }
}

extern "C" void kernel_launch(void* const* d_in, const int* in_sizes, int n_in,
                              void* d_out, int out_size, void* d_ws, size_t ws_size,
                              hipStream_t stream) {
    const float* x = (const float*)d_in[0];   // [8192, 256, 80]
    const float* W = (const float*)d_in[1];   // [25, 80]
    float* out = (float*)d_out;               // [8192, 5, 5]
    (void)in_sizes; (void)n_in; (void)out_size; (void)d_ws; (void)ws_size;

    capsule_mfma<<<dim3(8192), dim3(256), 0, stream>>>(x, W, out);
}